// Round 1
// baseline (721.303 us; speedup 1.0000x reference)
//
#include <hip/hip_runtime.h>
#include <math.h>

#define N_NODES 100000
#define N_EDGES 600000
#define IN_CH 128
#define HID 64
#define NEG_SLOPE 0.01f

typedef float4 f4;

__device__ __forceinline__ float lrelu(float x) {
    // for x<0: 0.01x > x, for x>=0: x >= 0.01x  -> max works
    return fmaxf(x, NEG_SLOPE * x);
}

// ---------------------------------------------------------------------------
// Detect whether edge_index is int64 (all high words of first 2048 entries 0)
// flag = 1 -> int64, flag = 0 -> int32
// ---------------------------------------------------------------------------
__global__ void detect_idx_kernel(const unsigned int* __restrict__ ei_words,
                                  int* __restrict__ flag) {
    __shared__ unsigned int red;
    if (threadIdx.x == 0) red = 0u;
    __syncthreads();
    unsigned int acc = 0u;
    #pragma unroll
    for (int i = 0; i < 8; ++i)
        acc |= ei_words[(i * 256 + threadIdx.x) * 2 + 1];
    atomicOr(&red, acc);
    __syncthreads();
    if (threadIdx.x == 0) *flag = (red == 0u) ? 1 : 0;
}

__device__ __forceinline__ int load_idx(const void* ei, int is64, int pos) {
    if (is64) return (int)((const long long*)ei)[pos];
    return ((const int*)ei)[pos];
}

// ---------------------------------------------------------------------------
// Node projection: pl[n][h] = sum_k W1l[h][k]*z[n][k] + b1l[h]  (same for pr)
// block = 256 (4 waves). Each wave does 4 nodes per iteration, lane = h.
// W staged in LDS with XOR-swizzled float4 layout (bank-uniform reads).
// ---------------------------------------------------------------------------
__global__ __launch_bounds__(256) void node_proj_kernel(
    const float* __restrict__ z, const float* __restrict__ W1l,
    const float* __restrict__ b1l, const float* __restrict__ W1r,
    const float* __restrict__ b1r, float* __restrict__ pl,
    float* __restrict__ pr) {
    __shared__ f4 Wl4[64 * 32];   // 32 KB
    __shared__ f4 Wr4[64 * 32];   // 32 KB
    __shared__ f4 zt[16 * 32];    // 8 KB, 16 nodes per block-iteration

    const int tid = threadIdx.x;

    // stage W (once per block), swizzled: slot(h,v) = h*32 + (v ^ (h&7))
    #pragma unroll
    for (int i = 0; i < 8; ++i) {
        int g = tid + i * 256;           // 0..2047 float4s
        int h = g >> 5, v = g & 31;
        int slot = (h << 5) | (v ^ (h & 7));
        Wl4[slot] = ((const f4*)W1l)[g];
        Wr4[slot] = ((const f4*)W1r)[g];
    }

    const int wave = tid >> 6;
    const int lane = tid & 63;
    const float bl = b1l[lane];
    const float br = b1r[lane];

    for (int base = blockIdx.x * 16; base < N_NODES; base += gridDim.x * 16) {
        __syncthreads();   // protect zt from previous iteration's readers
        #pragma unroll
        for (int i = 0; i < 2; ++i) {
            int s = tid + i * 256;       // 0..511
            int nl = s >> 5, v = s & 31;
            int node = base + nl;
            if (node < N_NODES) zt[s] = ((const f4*)z)[node * 32 + v];
        }
        __syncthreads();

        float accl[4] = {0.f, 0.f, 0.f, 0.f};
        float accr[4] = {0.f, 0.f, 0.f, 0.f};
        const int zb = (wave << 2) << 5;  // wave*4 nodes, *32 f4 each

        #pragma unroll
        for (int v = 0; v < 32; ++v) {
            f4 wl = Wl4[(lane << 5) | (v ^ (lane & 7))];
            f4 wr = Wr4[(lane << 5) | (v ^ (lane & 7))];
            #pragma unroll
            for (int j = 0; j < 4; ++j) {
                f4 zv = zt[zb + j * 32 + v];   // wave-uniform -> LDS broadcast
                accl[j] += wl.x * zv.x + wl.y * zv.y + wl.z * zv.z + wl.w * zv.w;
                accr[j] += wr.x * zv.x + wr.y * zv.y + wr.z * zv.z + wr.w * zv.w;
            }
        }

        #pragma unroll
        for (int j = 0; j < 4; ++j) {
            int node = base + (wave << 2) + j;
            if (node < N_NODES) {
                pl[node * 64 + lane] = accl[j] + bl;
                pr[node * 64 + lane] = accr[j] + br;
            }
        }
    }
}

// ---------------------------------------------------------------------------
// Edge kernel: 16 lanes per edge; lane c handles float4 chunk c of 16.
// out[e] = sigmoid(b2 + sum_h W2[h] * lrelu(pl[src][h] + pr[dst][h]))
// ---------------------------------------------------------------------------
__global__ __launch_bounds__(256) void edge_kernel(
    const void* __restrict__ ei, const int* __restrict__ flag,
    const float* __restrict__ pl, const float* __restrict__ pr,
    const float* __restrict__ W2, const float* __restrict__ b2,
    float* __restrict__ out) {
    int t = blockIdx.x * 256 + threadIdx.x;
    int e = t >> 4;
    int c = t & 15;
    if (e >= N_EDGES) return;
    const int is64 = *flag;                 // uniform, cached
    int src = load_idx(ei, is64, e);
    int dst = load_idx(ei, is64, N_EDGES + e);
    f4 a = ((const f4*)pl)[src * 16 + c];   // 16 lanes -> 256 B contiguous
    f4 b = ((const f4*)pr)[dst * 16 + c];
    f4 w = ((const f4*)W2)[c];
    float part = lrelu(a.x + b.x) * w.x + lrelu(a.y + b.y) * w.y +
                 lrelu(a.z + b.z) * w.z + lrelu(a.w + b.w) * w.w;
    part += __shfl_xor(part, 8, 16);
    part += __shfl_xor(part, 4, 16);
    part += __shfl_xor(part, 2, 16);
    part += __shfl_xor(part, 1, 16);
    if (c == 0) {
        float x = part + b2[0];
        out[e] = 1.f / (1.f + __expf(-x));
    }
}

// ---------------------------------------------------------------------------
// Fallback (workspace too small): one wave per edge, straight from z.
// ---------------------------------------------------------------------------
__global__ __launch_bounds__(256) void edge_fallback_kernel(
    const float* __restrict__ z, const void* __restrict__ ei,
    const int* __restrict__ flag, const float* __restrict__ W1l,
    const float* __restrict__ b1l, const float* __restrict__ W1r,
    const float* __restrict__ b1r, const float* __restrict__ W2,
    const float* __restrict__ b2, float* __restrict__ out) {
    __shared__ f4 Wl4[64 * 32];
    __shared__ f4 Wr4[64 * 32];
    const int tid = threadIdx.x;
    #pragma unroll
    for (int i = 0; i < 8; ++i) {
        int g = tid + i * 256;
        int h = g >> 5, v = g & 31;
        int slot = (h << 5) | (v ^ (h & 7));
        Wl4[slot] = ((const f4*)W1l)[g];
        Wr4[slot] = ((const f4*)W1r)[g];
    }
    __syncthreads();
    const int wave = tid >> 6, lane = tid & 63;
    int e = blockIdx.x * 4 + wave;
    if (e >= N_EDGES) return;
    const int is64 = (flag != nullptr) ? *flag : 0;
    int src = load_idx(ei, is64, e);
    int dst = load_idx(ei, is64, N_EDGES + e);
    float accl = 0.f, accr = 0.f;
    for (int v = 0; v < 32; ++v) {
        f4 wl = Wl4[(lane << 5) | (v ^ (lane & 7))];
        f4 wr = Wr4[(lane << 5) | (v ^ (lane & 7))];
        f4 zl = ((const f4*)z)[src * 32 + v];
        f4 zr = ((const f4*)z)[dst * 32 + v];
        accl += wl.x * zl.x + wl.y * zl.y + wl.z * zl.z + wl.w * zl.w;
        accr += wr.x * zr.x + wr.y * zr.y + wr.z * zr.z + wr.w * zr.w;
    }
    float h = lrelu(accl + b1l[lane] + accr + b1r[lane]) * W2[lane];
    #pragma unroll
    for (int off = 32; off; off >>= 1) h += __shfl_xor(h, off, 64);
    if (lane == 0) out[e] = 1.f / (1.f + __expf(-(h + b2[0])));
}

extern "C" void kernel_launch(void* const* d_in, const int* in_sizes, int n_in,
                              void* d_out, int out_size, void* d_ws,
                              size_t ws_size, hipStream_t stream) {
    const float* z   = (const float*)d_in[0];
    const void*  ei  = d_in[1];
    const float* W1l = (const float*)d_in[2];
    const float* b1l = (const float*)d_in[3];
    const float* W1r = (const float*)d_in[4];
    const float* b1r = (const float*)d_in[5];
    const float* W2  = (const float*)d_in[6];
    const float* b2  = (const float*)d_in[7];
    float* out = (float*)d_out;

    const size_t plpr_bytes = (size_t)N_NODES * HID * 2 * sizeof(float);
    const size_t need = plpr_bytes + 256;  // pl, pr, flag

    if (ws_size >= need) {
        float* pl = (float*)d_ws;
        float* pr = pl + (size_t)N_NODES * HID;
        int* flag = (int*)((char*)d_ws + plpr_bytes);
        detect_idx_kernel<<<1, 256, 0, stream>>>((const unsigned int*)ei, flag);
        node_proj_kernel<<<512, 256, 0, stream>>>(z, W1l, b1l, W1r, b1r, pl, pr);
        edge_kernel<<<(N_EDGES * 16 + 255) / 256, 256, 0, stream>>>(
            ei, flag, pl, pr, W2, b2, out);
    } else if (ws_size >= 256) {
        int* flag = (int*)d_ws;
        detect_idx_kernel<<<1, 256, 0, stream>>>((const unsigned int*)ei, flag);
        edge_fallback_kernel<<<(N_EDGES + 3) / 4, 256, 0, stream>>>(
            z, ei, flag, W1l, b1l, W1r, b1r, W2, b2, out);
    } else {
        edge_fallback_kernel<<<(N_EDGES + 3) / 4, 256, 0, stream>>>(
            z, ei, nullptr, W1l, b1l, W1r, b1r, W2, b2, out);
    }
}

// Round 2
// 113.769 us; speedup vs baseline: 6.3401x; 6.3401x over previous
//
#include <hip/hip_runtime.h>
#include <hip/hip_bf16.h>
#include <math.h>

#define N_NODES 100000
#define N_EDGES 600000
#define IN_CH 128
#define HID 64
#define NEG_SLOPE 0.01f

typedef float4 f4;
typedef unsigned short u16;
typedef unsigned int u32;

__device__ __forceinline__ float lrelu(float x) {
    return fmaxf(x, NEG_SLOPE * x);
}
__device__ __forceinline__ float uasf(u32 w) { return __uint_as_float(w); }
__device__ __forceinline__ u16 f2bf(float f) {  // round-to-nearest-even
    u32 x = __float_as_uint(f);
    return (u16)((x + 0x7fffu + ((x >> 16) & 1u)) >> 16);
}

// ---------------------------------------------------------------------------
// Detect whether edge_index is int64 (high words of first 2048 entries all 0)
// ---------------------------------------------------------------------------
__global__ void detect_idx_kernel(const u32* __restrict__ ei_words,
                                  int* __restrict__ flag) {
    __shared__ u32 red;
    if (threadIdx.x == 0) red = 0u;
    __syncthreads();
    u32 acc = 0u;
    #pragma unroll
    for (int i = 0; i < 8; ++i)
        acc |= ei_words[(i * 256 + threadIdx.x) * 2 + 1];
    atomicOr(&red, acc);
    __syncthreads();
    if (threadIdx.x == 0) *flag = (red == 0u) ? 1 : 0;
}

__device__ __forceinline__ int load_idx(const void* ei, int is64, int pos) {
    if (is64) return (int)((const long long*)ei)[pos];
    return ((const int*)ei)[pos];
}

// ---------------------------------------------------------------------------
// Node projection: pl[n][h] = W1l[h]·z[n] + b1l[h]  (same for pr), bf16 out.
// block = 256 (4 waves), lane = h. 32 nodes per block-iteration (8/wave).
// LDS: CW[k4][h] = {W1l[h][4k4..], W1r[h][4k4..]} as 8 bf16 (one b128/step),
//      zt fp32 [32 nodes][32 f4]. 48 KB total -> 3 blocks/CU.
// Partial unroll keeps VGPR low (round-1 lesson: full unroll -> 256 VGPR ->
// 650 MB scratch-spill traffic -> 727 us).
// ---------------------------------------------------------------------------
__global__ __launch_bounds__(256) void node_proj_kernel(
    const float* __restrict__ z, const float* __restrict__ W1l,
    const float* __restrict__ b1l, const float* __restrict__ W1r,
    const float* __restrict__ b1r, u16* __restrict__ plb,
    u16* __restrict__ prb) {
    __shared__ uint4 CW[32 * 64];  // 32 KB
    __shared__ f4 zt[32 * 32];     // 16 KB

    const int tid = threadIdx.x;

    // stage combined W^T (bf16-packed), once per block
    #pragma unroll
    for (int i = 0; i < 8; ++i) {
        int g = tid + i * 256;  // g = k4*64 + h, 0..2047
        int k4 = g >> 6, h = g & 63;
        f4 l = ((const f4*)W1l)[h * 32 + k4];
        f4 r = ((const f4*)W1r)[h * 32 + k4];
        uint4 p;
        p.x = (u32)f2bf(l.x) | ((u32)f2bf(l.y) << 16);
        p.y = (u32)f2bf(l.z) | ((u32)f2bf(l.w) << 16);
        p.z = (u32)f2bf(r.x) | ((u32)f2bf(r.y) << 16);
        p.w = (u32)f2bf(r.z) | ((u32)f2bf(r.w) << 16);
        CW[g] = p;
    }

    const int wave = tid >> 6;
    const int lane = tid & 63;
    const float bl = b1l[lane];
    const float br = b1r[lane];

    // 100000 % 32 == 0 -> no tail guards needed
    for (int base = blockIdx.x * 32; base < N_NODES; base += gridDim.x * 32) {
        __syncthreads();  // protect zt from previous iteration's readers
        #pragma unroll
        for (int i = 0; i < 4; ++i) {
            int s = tid + i * 256;  // 0..1023, contiguous
            zt[s] = ((const f4*)z)[base * 32 + s];
        }
        __syncthreads();

        float accl[8] = {0.f, 0.f, 0.f, 0.f, 0.f, 0.f, 0.f, 0.f};
        float accr[8] = {0.f, 0.f, 0.f, 0.f, 0.f, 0.f, 0.f, 0.f};
        const int zb = (wave << 3) << 5;  // wave*8 nodes, *32 f4 each

        #pragma unroll 4
        for (int k4 = 0; k4 < 32; ++k4) {
            uint4 w = CW[(k4 << 6) + lane];  // 64 lanes x 16B contiguous
            float wl0 = uasf(w.x << 16), wl1 = uasf(w.x & 0xffff0000u);
            float wl2 = uasf(w.y << 16), wl3 = uasf(w.y & 0xffff0000u);
            float wr0 = uasf(w.z << 16), wr1 = uasf(w.z & 0xffff0000u);
            float wr2 = uasf(w.w << 16), wr3 = uasf(w.w & 0xffff0000u);
            #pragma unroll
            for (int j = 0; j < 8; ++j) {
                f4 zv = zt[zb + (j << 5) + k4];  // wave-uniform -> broadcast
                accl[j] += wl0 * zv.x + wl1 * zv.y + wl2 * zv.z + wl3 * zv.w;
                accr[j] += wr0 * zv.x + wr1 * zv.y + wr2 * zv.z + wr3 * zv.w;
            }
        }

        #pragma unroll
        for (int j = 0; j < 8; ++j) {
            int node = base + (wave << 3) + j;
            plb[node * 64 + lane] = f2bf(accl[j] + bl);
            prb[node * 64 + lane] = f2bf(accr[j] + br);
        }
    }
}

// ---------------------------------------------------------------------------
// Edge kernel: 8 lanes/edge; lane c reads 16B (8 bf16) of pl[src], pr[dst].
// Each row is 128 B = one cache line, line-aligned.
// ---------------------------------------------------------------------------
__global__ __launch_bounds__(256) void edge_kernel(
    const void* __restrict__ ei, const int* __restrict__ flag,
    const u16* __restrict__ plb, const u16* __restrict__ prb,
    const float* __restrict__ W2, const float* __restrict__ b2,
    float* __restrict__ out) {
    int t = blockIdx.x * 256 + threadIdx.x;
    int e = t >> 3;
    int c = t & 7;
    if (e >= N_EDGES) return;
    const int is64 = *flag;  // uniform
    int src = load_idx(ei, is64, e);
    int dst = load_idx(ei, is64, N_EDGES + e);
    uint4 a = ((const uint4*)plb)[src * 8 + c];
    uint4 b = ((const uint4*)prb)[dst * 8 + c];
    f4 w0 = ((const f4*)W2)[c * 2];
    f4 w1 = ((const f4*)W2)[c * 2 + 1];
    float s;
    s  = lrelu(uasf(a.x << 16) + uasf(b.x << 16)) * w0.x;
    s += lrelu(uasf(a.x & 0xffff0000u) + uasf(b.x & 0xffff0000u)) * w0.y;
    s += lrelu(uasf(a.y << 16) + uasf(b.y << 16)) * w0.z;
    s += lrelu(uasf(a.y & 0xffff0000u) + uasf(b.y & 0xffff0000u)) * w0.w;
    s += lrelu(uasf(a.z << 16) + uasf(b.z << 16)) * w1.x;
    s += lrelu(uasf(a.z & 0xffff0000u) + uasf(b.z & 0xffff0000u)) * w1.y;
    s += lrelu(uasf(a.w << 16) + uasf(b.w << 16)) * w1.z;
    s += lrelu(uasf(a.w & 0xffff0000u) + uasf(b.w & 0xffff0000u)) * w1.w;
    s += __shfl_xor(s, 4, 8);
    s += __shfl_xor(s, 2, 8);
    s += __shfl_xor(s, 1, 8);
    if (c == 0) {
        float x = s + b2[0];
        out[e] = 1.f / (1.f + __expf(-x));
    }
}

// ---------------------------------------------------------------------------
// Fallback (workspace too small): one wave per edge, straight from z (fp32).
// ---------------------------------------------------------------------------
__global__ __launch_bounds__(256) void edge_fallback_kernel(
    const float* __restrict__ z, const void* __restrict__ ei,
    const int* __restrict__ flag, const float* __restrict__ W1l,
    const float* __restrict__ b1l, const float* __restrict__ W1r,
    const float* __restrict__ b1r, const float* __restrict__ W2,
    const float* __restrict__ b2, float* __restrict__ out) {
    __shared__ f4 Wl4[64 * 32];
    __shared__ f4 Wr4[64 * 32];
    const int tid = threadIdx.x;
    #pragma unroll
    for (int i = 0; i < 8; ++i) {
        int g = tid + i * 256;
        int h = g >> 5, v = g & 31;
        int slot = (h << 5) | (v ^ (h & 7));
        Wl4[slot] = ((const f4*)W1l)[g];
        Wr4[slot] = ((const f4*)W1r)[g];
    }
    __syncthreads();
    const int wave = tid >> 6, lane = tid & 63;
    int e = blockIdx.x * 4 + wave;
    if (e >= N_EDGES) return;
    const int is64 = (flag != nullptr) ? *flag : 0;
    int src = load_idx(ei, is64, e);
    int dst = load_idx(ei, is64, N_EDGES + e);
    float accl = 0.f, accr = 0.f;
    #pragma unroll 4
    for (int v = 0; v < 32; ++v) {
        f4 wl = Wl4[(lane << 5) | (v ^ (lane & 7))];
        f4 wr = Wr4[(lane << 5) | (v ^ (lane & 7))];
        f4 zl = ((const f4*)z)[src * 32 + v];
        f4 zr = ((const f4*)z)[dst * 32 + v];
        accl += wl.x * zl.x + wl.y * zl.y + wl.z * zl.z + wl.w * zl.w;
        accr += wr.x * zr.x + wr.y * zr.y + wr.z * zr.z + wr.w * zr.w;
    }
    float h = lrelu(accl + b1l[lane] + accr + b1r[lane]) * W2[lane];
    #pragma unroll
    for (int off = 32; off; off >>= 1) h += __shfl_xor(h, off, 64);
    if (lane == 0) out[e] = 1.f / (1.f + __expf(-(h + b2[0])));
}

extern "C" void kernel_launch(void* const* d_in, const int* in_sizes, int n_in,
                              void* d_out, int out_size, void* d_ws,
                              size_t ws_size, hipStream_t stream) {
    const float* z   = (const float*)d_in[0];
    const void*  ei  = d_in[1];
    const float* W1l = (const float*)d_in[2];
    const float* b1l = (const float*)d_in[3];
    const float* W1r = (const float*)d_in[4];
    const float* b1r = (const float*)d_in[5];
    const float* W2  = (const float*)d_in[6];
    const float* b2  = (const float*)d_in[7];
    float* out = (float*)d_out;

    const size_t pl_bytes = (size_t)N_NODES * HID * sizeof(u16);  // 12.8 MB
    const size_t need = 2 * pl_bytes + 256;

    if (ws_size >= need) {
        u16* plb = (u16*)d_ws;
        u16* prb = (u16*)((char*)d_ws + pl_bytes);
        int* flag = (int*)((char*)d_ws + 2 * pl_bytes);
        detect_idx_kernel<<<1, 256, 0, stream>>>((const u32*)ei, flag);
        node_proj_kernel<<<768, 256, 0, stream>>>(z, W1l, b1l, W1r, b1r, plb, prb);
        edge_kernel<<<(N_EDGES * 8 + 255) / 256, 256, 0, stream>>>(
            ei, flag, plb, prb, W2, b2, out);
    } else if (ws_size >= 256) {
        int* flag = (int*)d_ws;
        detect_idx_kernel<<<1, 256, 0, stream>>>((const u32*)ei, flag);
        edge_fallback_kernel<<<(N_EDGES + 3) / 4, 256, 0, stream>>>(
            z, ei, flag, W1l, b1l, W1r, b1r, W2, b2, out);
    } else {
        edge_fallback_kernel<<<(N_EDGES + 3) / 4, 256, 0, stream>>>(
            z, ei, nullptr, W1l, b1l, W1r, b1r, W2, b2, out);
    }
}

// Round 3
// 47.132 us; speedup vs baseline: 15.3038x; 2.4138x over previous
//
#include <hip/hip_runtime.h>
#include <math.h>

#define N_NODES 100000
#define N_EDGES 600000
#define IN_CH 128
#define HID 64
#define NEG_SLOPE 0.01f

typedef float4 f4;
typedef unsigned short u16;
typedef unsigned int u32;
typedef __attribute__((ext_vector_type(8))) short bf16x8;   // 8 bf16 (4 VGPRs)
typedef __attribute__((ext_vector_type(4))) float f32x4;    // MFMA acc

__device__ __forceinline__ float lrelu(float x) {
    return fmaxf(x, NEG_SLOPE * x);
}
__device__ __forceinline__ float uasf(u32 w) { return __uint_as_float(w); }
__device__ __forceinline__ u16 f2bf(float f) {  // round-to-nearest-even
    u32 x = __float_as_uint(f);
    return (u16)((x + 0x7fffu + ((x >> 16) & 1u)) >> 16);
}
__device__ __forceinline__ u32 pack2(float a, float b) {
    return (u32)f2bf(a) | ((u32)f2bf(b) << 16);
}

__device__ __forceinline__ int load_idx(const void* ei, int is64, int pos) {
    if (is64) return (int)((const long long*)ei)[pos];
    return ((const int*)ei)[pos];
}

// ---------------------------------------------------------------------------
// MFMA node projection. pcomb[n][0:64] = W1l·z[n]+b1l, [64:128] = W1r·z[n]+b1r
// (bf16). Block = 256 thr (4 waves), tile = 64 nodes × 128 outs, K=128.
// LDS: wt = W_comb bf16 [128 rows][16 granules of 16B], XOR-swizzled;
//      zt = z tile bf16 [64 rows][16 granules], same swizzle. 48 KB -> 3 blk/CU.
// Orientation: acc = mfma(W_frag, z_frag, acc) -> D row = h_local (4g+reg),
// D col = node (lane&15)  [C/D map verified: col=lane&15, row=4*(lane>>4)+reg]
// -> each lane owns ONE node row, 4 consecutive h per c-tile -> 8B stores.
// K-slot placement k = 8*(lane>>4)+i used identically for both operands
// (any shared bijection is correct: dot-product is permutation-invariant).
// Block 0 additionally detects int32 vs int64 edge_index into *flag.
// ---------------------------------------------------------------------------
__global__ __launch_bounds__(256) void node_proj_kernel(
    const float* __restrict__ z, const float* __restrict__ W1l,
    const float* __restrict__ b1l, const float* __restrict__ W1r,
    const float* __restrict__ b1r, const u32* __restrict__ ei_words,
    int* __restrict__ flag, u16* __restrict__ pcomb) {
    __shared__ uint4 wt[128 * 16];  // 32 KB
    __shared__ uint4 zt[64 * 16];   // 16 KB
    __shared__ u32 red;

    const int tid = threadIdx.x;

    if (blockIdx.x == 0) {  // int64 detect (high words of first 2048 entries)
        if (tid == 0) red = 0u;
        __syncthreads();
        u32 acc = 0u;
        #pragma unroll
        for (int i = 0; i < 8; ++i)
            acc |= ei_words[(i * 256 + tid) * 2 + 1];
        atomicOr(&red, acc);
        __syncthreads();
        if (tid == 0) *flag = (red == 0u) ? 1 : 0;
    }

    // stage W_comb as bf16, swizzled granules: slot = row*16 + (gr ^ (row&15))
    #pragma unroll
    for (int i = 0; i < 8; ++i) {
        int gidx = tid + i * 256;        // row*16 + gr, 0..2047
        int row = gidx >> 4, gr = gidx & 15;
        const float* wsrc = (row < 64) ? (W1l + row * IN_CH)
                                       : (W1r + (row - 64) * IN_CH);
        f4 a = ((const f4*)wsrc)[gr * 2];
        f4 b = ((const f4*)wsrc)[gr * 2 + 1];
        uint4 p;
        p.x = pack2(a.x, a.y); p.y = pack2(a.z, a.w);
        p.z = pack2(b.x, b.y); p.w = pack2(b.z, b.w);
        wt[(row << 4) | (gr ^ (row & 15))] = p;
    }

    // stage z tile (64 nodes), bf16, same swizzle
    const int base = blockIdx.x * 64;
    #pragma unroll
    for (int i = 0; i < 4; ++i) {
        int gidx = tid + i * 256;        // row*16 + gr, 0..1023
        int row = gidx >> 4, gr = gidx & 15;
        int node = base + row;
        if (node >= N_NODES) node = N_NODES - 1;  // pad reads, stores guarded
        f4 a = ((const f4*)z)[node * 32 + gr * 2];
        f4 b = ((const f4*)z)[node * 32 + gr * 2 + 1];
        uint4 p;
        p.x = pack2(a.x, a.y); p.y = pack2(a.z, a.w);
        p.z = pack2(b.x, b.y); p.w = pack2(b.z, b.w);
        zt[(row << 4) | (gr ^ (row & 15))] = p;
    }
    __syncthreads();

    const int wave = tid >> 6, lane = tid & 63;
    const int m = lane & 15, g = lane >> 4;

    f32x4 acc[8];
    #pragma unroll
    for (int c = 0; c < 8; ++c) acc[c] = {0.f, 0.f, 0.f, 0.f};

    const int zrow = (wave << 4) | m;    // local node row; zrow&15 == m
    #pragma unroll
    for (int kk = 0; kk < 4; ++kk) {
        int gran = (kk << 2) | g;        // granule 0..15 (8 bf16 each)
        bf16x8 zf = *(const bf16x8*)&zt[(zrow << 4) | (gran ^ m)];
        #pragma unroll
        for (int c = 0; c < 8; ++c) {
            int wrow = (c << 4) | m;     // wrow&15 == m
            bf16x8 wf = *(const bf16x8*)&wt[(wrow << 4) | (gran ^ m)];
            acc[c] = __builtin_amdgcn_mfma_f32_16x16x32_bf16(wf, zf, acc[c],
                                                             0, 0, 0);
        }
    }

    const int node = base + (wave << 4) + m;
    if (node < N_NODES) {
        u16* orow = pcomb + (size_t)node * 128;
        #pragma unroll
        for (int c = 0; c < 8; ++c) {
            int col = (c << 4) + (g << 2);  // h_comb of acc[c][0]
            const float* bsrc = (col < 64) ? (b1l + col) : (b1r + (col - 64));
            f4 bb = *(const f4*)bsrc;
            uint2 v;
            v.x = pack2(acc[c][0] + bb.x, acc[c][1] + bb.y);
            v.y = pack2(acc[c][2] + bb.z, acc[c][3] + bb.w);
            *(uint2*)(orow + col) = v;      // 8B, aligned
        }
    }
}

// ---------------------------------------------------------------------------
// Edge kernel: 8 lanes/edge; lane c reads 16B of pl half (src) + pr half (dst)
// pcomb row = 256 B; each half = 128 B = one cache line.
// ---------------------------------------------------------------------------
__global__ __launch_bounds__(256) void edge_kernel(
    const void* __restrict__ ei, const int* __restrict__ flag,
    const u16* __restrict__ pcomb, const float* __restrict__ W2,
    const float* __restrict__ b2, float* __restrict__ out) {
    int t = blockIdx.x * 256 + threadIdx.x;
    int e = t >> 3;
    int c = t & 7;
    if (e >= N_EDGES) return;
    const int is64 = *flag;  // uniform
    int src = load_idx(ei, is64, e);
    int dst = load_idx(ei, is64, N_EDGES + e);
    uint4 a = ((const uint4*)pcomb)[src * 16 + c];
    uint4 b = ((const uint4*)pcomb)[dst * 16 + 8 + c];
    f4 w0 = ((const f4*)W2)[c * 2];
    f4 w1 = ((const f4*)W2)[c * 2 + 1];
    float s;
    s  = lrelu(uasf(a.x << 16) + uasf(b.x << 16)) * w0.x;
    s += lrelu(uasf(a.x & 0xffff0000u) + uasf(b.x & 0xffff0000u)) * w0.y;
    s += lrelu(uasf(a.y << 16) + uasf(b.y << 16)) * w0.z;
    s += lrelu(uasf(a.y & 0xffff0000u) + uasf(b.y & 0xffff0000u)) * w0.w;
    s += lrelu(uasf(a.z << 16) + uasf(b.z << 16)) * w1.x;
    s += lrelu(uasf(a.z & 0xffff0000u) + uasf(b.z & 0xffff0000u)) * w1.y;
    s += lrelu(uasf(a.w << 16) + uasf(b.w << 16)) * w1.z;
    s += lrelu(uasf(a.w & 0xffff0000u) + uasf(b.w & 0xffff0000u)) * w1.w;
    s += __shfl_xor(s, 4, 8);
    s += __shfl_xor(s, 2, 8);
    s += __shfl_xor(s, 1, 8);
    if (c == 0) {
        float x = s + b2[0];
        out[e] = 1.f / (1.f + __expf(-x));
    }
}

// ---------------------------------------------------------------------------
// Fallback path (workspace too small) — round-2 proven kernels.
// ---------------------------------------------------------------------------
__global__ void detect_idx_kernel(const u32* __restrict__ ei_words,
                                  int* __restrict__ flag) {
    __shared__ u32 red;
    if (threadIdx.x == 0) red = 0u;
    __syncthreads();
    u32 acc = 0u;
    #pragma unroll
    for (int i = 0; i < 8; ++i)
        acc |= ei_words[(i * 256 + threadIdx.x) * 2 + 1];
    atomicOr(&red, acc);
    __syncthreads();
    if (threadIdx.x == 0) *flag = (red == 0u) ? 1 : 0;
}

__global__ __launch_bounds__(256) void edge_fallback_kernel(
    const float* __restrict__ z, const void* __restrict__ ei,
    const int* __restrict__ flag, const float* __restrict__ W1l,
    const float* __restrict__ b1l, const float* __restrict__ W1r,
    const float* __restrict__ b1r, const float* __restrict__ W2,
    const float* __restrict__ b2, float* __restrict__ out) {
    __shared__ f4 Wl4[64 * 32];
    __shared__ f4 Wr4[64 * 32];
    const int tid = threadIdx.x;
    #pragma unroll
    for (int i = 0; i < 8; ++i) {
        int gg = tid + i * 256;
        int h = gg >> 5, v = gg & 31;
        int slot = (h << 5) | (v ^ (h & 7));
        Wl4[slot] = ((const f4*)W1l)[gg];
        Wr4[slot] = ((const f4*)W1r)[gg];
    }
    __syncthreads();
    const int wave = tid >> 6, lane = tid & 63;
    int e = blockIdx.x * 4 + wave;
    if (e >= N_EDGES) return;
    const int is64 = (flag != nullptr) ? *flag : 0;
    int src = load_idx(ei, is64, e);
    int dst = load_idx(ei, is64, N_EDGES + e);
    float accl = 0.f, accr = 0.f;
    #pragma unroll 4
    for (int v = 0; v < 32; ++v) {
        f4 wl = Wl4[(lane << 5) | (v ^ (lane & 7))];
        f4 wr = Wr4[(lane << 5) | (v ^ (lane & 7))];
        f4 zl = ((const f4*)z)[src * 32 + v];
        f4 zr = ((const f4*)z)[dst * 32 + v];
        accl += wl.x * zl.x + wl.y * zl.y + wl.z * zl.z + wl.w * zl.w;
        accr += wr.x * zr.x + wr.y * zr.y + wr.z * zr.z + wr.w * zr.w;
    }
    float h = lrelu(accl + b1l[lane] + accr + b1r[lane]) * W2[lane];
    #pragma unroll
    for (int off = 32; off; off >>= 1) h += __shfl_xor(h, off, 64);
    if (lane == 0) out[e] = 1.f / (1.f + __expf(-(h + b2[0])));
}

extern "C" void kernel_launch(void* const* d_in, const int* in_sizes, int n_in,
                              void* d_out, int out_size, void* d_ws,
                              size_t ws_size, hipStream_t stream) {
    const float* z   = (const float*)d_in[0];
    const void*  ei  = d_in[1];
    const float* W1l = (const float*)d_in[2];
    const float* b1l = (const float*)d_in[3];
    const float* W1r = (const float*)d_in[4];
    const float* b1r = (const float*)d_in[5];
    const float* W2  = (const float*)d_in[6];
    const float* b2  = (const float*)d_in[7];
    float* out = (float*)d_out;

    const size_t pcomb_bytes = (size_t)N_NODES * 128 * sizeof(u16);  // 25.6 MB
    const size_t need = pcomb_bytes + 256;

    if (ws_size >= need) {
        u16* pcomb = (u16*)d_ws;
        int* flag = (int*)((char*)d_ws + pcomb_bytes);
        node_proj_kernel<<<(N_NODES + 63) / 64, 256, 0, stream>>>(
            z, W1l, b1l, W1r, b1r, (const u32*)ei, flag, pcomb);
        edge_kernel<<<(N_EDGES * 8 + 255) / 256, 256, 0, stream>>>(
            ei, flag, pcomb, W2, b2, out);
    } else if (ws_size >= 256) {
        int* flag = (int*)d_ws;
        detect_idx_kernel<<<1, 256, 0, stream>>>((const u32*)ei, flag);
        edge_fallback_kernel<<<(N_EDGES + 3) / 4, 256, 0, stream>>>(
            z, ei, flag, W1l, b1l, W1r, b1r, W2, b2, out);
    } else {
        edge_fallback_kernel<<<(N_EDGES + 3) / 4, 256, 0, stream>>>(
            z, ei, nullptr, W1l, b1l, W1r, b1r, W2, b2, out);
    }
}

// Round 4
// 45.673 us; speedup vs baseline: 15.7929x; 1.0320x over previous
//
#include <hip/hip_runtime.h>
#include <math.h>

#define N_NODES 100000
#define N_EDGES 600000
#define IN_CH 128
#define HID 64
#define NEG_SLOPE 0.01f

typedef float4 f4;
typedef unsigned short u16;
typedef unsigned int u32;
typedef __attribute__((ext_vector_type(8))) short bf16x8;   // 8 bf16 (4 VGPRs)
typedef __attribute__((ext_vector_type(4))) float f32x4;    // MFMA acc

__device__ __forceinline__ float lrelu(float x) {
    return fmaxf(x, NEG_SLOPE * x);
}
__device__ __forceinline__ float uasf(u32 w) { return __uint_as_float(w); }

// HW packed conversion: D[15:0]=bf16(lo), D[31:16]=bf16(hi). One VALU op
// (vs ~10 for the manual RNE pack that made round-2/3 staging VALU-bound).
__device__ __forceinline__ u32 cvt_pk(float lo, float hi) {
    u32 r;
    asm("v_cvt_pk_bf16_f32 %0, %1, %2" : "=v"(r) : "v"(lo), "v"(hi));
    return r;
}
// software fallback pack (used only in ws-too-small fallback path)
__device__ __forceinline__ u16 f2bf(float f) {
    u32 x = __float_as_uint(f);
    return (u16)((x + 0x7fffu + ((x >> 16) & 1u)) >> 16);
}

__device__ __forceinline__ int load_idx(const void* ei, int is64, int pos) {
    if (is64) return (int)((const long long*)ei)[pos];
    return ((const int*)ei)[pos];
}

// ---------------------------------------------------------------------------
// MFMA node projection. pcomb[n][0:64] = W1l·z[n]+b1l, [64:128] = W1r·z[n]+b1r
// (bf16). Block = 256 thr (4 waves), tile = 64 nodes × 128 outs, K=128.
// Wave tile = 64 nodes × 32 h-cols (acc[4][2]) -> 24 ds_read_b128/thread
// (vs 36 for the 16×128 shape), 32 MFMAs.
// LDS XOR swizzle slot = (row<<4) | (gr ^ (row&15)) — conflict-free b128 reads
// (0 bank conflicts measured in rounds 2-3).
// Orientation invariants (verified passing in r3, absmax 3.9e-3):
//   acc = mfma(W_frag, z_frag, acc); B-frag loaded from z-row (16t+m) -> D col
//   m owns node base+16t+m; A-frag from W-row (R0+m) -> D row 4g+j is h R0+4g+j.
//   K-slot bijection gran=(kk<<2)|g identical for both operands (dot-product
//   permutation invariance).
// Block 0 additionally detects int32 vs int64 edge_index into *flag.
// ---------------------------------------------------------------------------
__global__ __launch_bounds__(256) void node_proj_kernel(
    const float* __restrict__ z, const float* __restrict__ W1l,
    const float* __restrict__ b1l, const float* __restrict__ W1r,
    const float* __restrict__ b1r, const u32* __restrict__ ei_words,
    int* __restrict__ flag, u16* __restrict__ pcomb) {
    __shared__ uint4 wt[128 * 16];  // 32 KB
    __shared__ uint4 zt[64 * 16];   // 16 KB
    __shared__ u32 red;

    const int tid = threadIdx.x;

    if (blockIdx.x == 0) {  // int64 detect (high words of first 2048 entries)
        if (tid == 0) red = 0u;
        __syncthreads();
        u32 acc = 0u;
        #pragma unroll
        for (int i = 0; i < 8; ++i)
            acc |= ei_words[(i * 256 + tid) * 2 + 1];
        atomicOr(&red, acc);
        __syncthreads();
        if (tid == 0) *flag = (red == 0u) ? 1 : 0;
    }

    // stage W_comb as bf16, swizzled
    #pragma unroll
    for (int i = 0; i < 8; ++i) {
        int gidx = tid + i * 256;        // row*16 + gr, 0..2047
        int row = gidx >> 4, gr = gidx & 15;
        const float* wsrc = (row < 64) ? (W1l + row * IN_CH)
                                       : (W1r + (row - 64) * IN_CH);
        f4 a = ((const f4*)wsrc)[gr * 2];
        f4 b = ((const f4*)wsrc)[gr * 2 + 1];
        uint4 p;
        p.x = cvt_pk(a.x, a.y); p.y = cvt_pk(a.z, a.w);
        p.z = cvt_pk(b.x, b.y); p.w = cvt_pk(b.z, b.w);
        wt[(row << 4) | (gr ^ (row & 15))] = p;
    }

    // stage z tile (64 nodes), bf16, same swizzle
    const int base = blockIdx.x * 64;
    #pragma unroll
    for (int i = 0; i < 4; ++i) {
        int gidx = tid + i * 256;        // row*16 + gr, 0..1023
        int row = gidx >> 4, gr = gidx & 15;
        int node = base + row;
        if (node >= N_NODES) node = N_NODES - 1;  // pad reads, stores guarded
        f4 a = ((const f4*)z)[node * 32 + gr * 2];
        f4 b = ((const f4*)z)[node * 32 + gr * 2 + 1];
        uint4 p;
        p.x = cvt_pk(a.x, a.y); p.y = cvt_pk(a.z, a.w);
        p.z = cvt_pk(b.x, b.y); p.w = cvt_pk(b.z, b.w);
        zt[(row << 4) | (gr ^ (row & 15))] = p;
    }
    __syncthreads();

    const int wave = tid >> 6, lane = tid & 63;
    const int m = lane & 15, g = lane >> 4;

    f32x4 acc[4][2];
    #pragma unroll
    for (int n4 = 0; n4 < 4; ++n4)
        #pragma unroll
        for (int c2 = 0; c2 < 2; ++c2) acc[n4][c2] = {0.f, 0.f, 0.f, 0.f};

    #pragma unroll
    for (int kk = 0; kk < 4; ++kk) {
        const int gran = (kk << 2) | g;
        bf16x8 zf[4], wf[2];
        #pragma unroll
        for (int n4 = 0; n4 < 4; ++n4)
            zf[n4] = *(const bf16x8*)&zt[((((n4 << 4) | m)) << 4) | (gran ^ m)];
        #pragma unroll
        for (int c2 = 0; c2 < 2; ++c2) {
            int R = (wave << 5) + (c2 << 4) + m;   // R & 15 == m
            wf[c2] = *(const bf16x8*)&wt[(R << 4) | (gran ^ m)];
        }
        #pragma unroll
        for (int n4 = 0; n4 < 4; ++n4)
            #pragma unroll
            for (int c2 = 0; c2 < 2; ++c2)
                acc[n4][c2] = __builtin_amdgcn_mfma_f32_16x16x32_bf16(
                    wf[c2], zf[n4], acc[n4][c2], 0, 0, 0);
    }

    // epilogue: bias + cvt_pk pack + 8B stores
    const int colbase = wave << 5;
    #pragma unroll
    for (int c2 = 0; c2 < 2; ++c2) {
        const int col0 = colbase + (c2 << 4) + (g << 2);
        const float* bsrc = (colbase < 64) ? (b1l + col0) : (b1r + col0 - 64);
        f4 bb = *(const f4*)bsrc;
        #pragma unroll
        for (int n4 = 0; n4 < 4; ++n4) {
            int node = base + (n4 << 4) + m;
            if (node < N_NODES) {
                uint2 v;
                v.x = cvt_pk(acc[n4][c2][0] + bb.x, acc[n4][c2][1] + bb.y);
                v.y = cvt_pk(acc[n4][c2][2] + bb.z, acc[n4][c2][3] + bb.w);
                *(uint2*)(pcomb + (size_t)node * 128 + col0) = v;
            }
        }
    }
}

// ---------------------------------------------------------------------------
// Edge kernel: 8 lanes per edge-PAIR slot; each thread handles 2 adjacent
// edges (paired 16B index load, 4 independent gathers in flight, float2 out).
// ---------------------------------------------------------------------------
__device__ __forceinline__ float edot(uint4 a, uint4 b, f4 w0, f4 w1) {
    float s;
    s  = lrelu(uasf(a.x << 16) + uasf(b.x << 16)) * w0.x;
    s += lrelu(uasf(a.x & 0xffff0000u) + uasf(b.x & 0xffff0000u)) * w0.y;
    s += lrelu(uasf(a.y << 16) + uasf(b.y << 16)) * w0.z;
    s += lrelu(uasf(a.y & 0xffff0000u) + uasf(b.y & 0xffff0000u)) * w0.w;
    s += lrelu(uasf(a.z << 16) + uasf(b.z << 16)) * w1.x;
    s += lrelu(uasf(a.z & 0xffff0000u) + uasf(b.z & 0xffff0000u)) * w1.y;
    s += lrelu(uasf(a.w << 16) + uasf(b.w << 16)) * w1.z;
    s += lrelu(uasf(a.w & 0xffff0000u) + uasf(b.w & 0xffff0000u)) * w1.w;
    return s;
}

__global__ __launch_bounds__(256) void edge_kernel(
    const void* __restrict__ ei, const int* __restrict__ flag,
    const u16* __restrict__ pcomb, const float* __restrict__ W2,
    const float* __restrict__ b2, float* __restrict__ out) {
    int t = blockIdx.x * 256 + threadIdx.x;
    int pair = t >> 3;
    int c = t & 7;
    if (pair >= N_EDGES / 2) return;
    const int is64 = *flag;  // uniform
    int s0, s1, d0, d1;
    if (is64) {
        const longlong2* p = (const longlong2*)ei;
        longlong2 sp = p[pair];
        longlong2 dp = p[N_EDGES / 2 + pair];
        s0 = (int)sp.x; s1 = (int)sp.y; d0 = (int)dp.x; d1 = (int)dp.y;
    } else {
        const int2* p = (const int2*)ei;
        int2 sp = p[pair];
        int2 dp = p[N_EDGES / 2 + pair];
        s0 = sp.x; s1 = sp.y; d0 = dp.x; d1 = dp.y;
    }
    const uint4* pc4 = (const uint4*)pcomb;
    uint4 a0 = pc4[s0 * 16 + c];
    uint4 b0 = pc4[d0 * 16 + 8 + c];
    uint4 a1 = pc4[s1 * 16 + c];
    uint4 b1 = pc4[d1 * 16 + 8 + c];
    f4 w0 = ((const f4*)W2)[c * 2];
    f4 w1 = ((const f4*)W2)[c * 2 + 1];
    float r0 = edot(a0, b0, w0, w1);
    float r1 = edot(a1, b1, w0, w1);
    r0 += __shfl_xor(r0, 4, 8);
    r0 += __shfl_xor(r0, 2, 8);
    r0 += __shfl_xor(r0, 1, 8);
    r1 += __shfl_xor(r1, 4, 8);
    r1 += __shfl_xor(r1, 2, 8);
    r1 += __shfl_xor(r1, 1, 8);
    if (c == 0) {
        float bb = b2[0];
        float2 o;
        o.x = 1.f / (1.f + __expf(-(r0 + bb)));
        o.y = 1.f / (1.f + __expf(-(r1 + bb)));
        *(float2*)(out + pair * 2) = o;
    }
}

// ---------------------------------------------------------------------------
// Fallback path (workspace too small) — round-2 proven kernels.
// ---------------------------------------------------------------------------
__global__ void detect_idx_kernel(const u32* __restrict__ ei_words,
                                  int* __restrict__ flag) {
    __shared__ u32 red;
    if (threadIdx.x == 0) red = 0u;
    __syncthreads();
    u32 acc = 0u;
    #pragma unroll
    for (int i = 0; i < 8; ++i)
        acc |= ei_words[(i * 256 + threadIdx.x) * 2 + 1];
    atomicOr(&red, acc);
    __syncthreads();
    if (threadIdx.x == 0) *flag = (red == 0u) ? 1 : 0;
}

__global__ __launch_bounds__(256) void edge_fallback_kernel(
    const float* __restrict__ z, const void* __restrict__ ei,
    const int* __restrict__ flag, const float* __restrict__ W1l,
    const float* __restrict__ b1l, const float* __restrict__ W1r,
    const float* __restrict__ b1r, const float* __restrict__ W2,
    const float* __restrict__ b2, float* __restrict__ out) {
    __shared__ f4 Wl4[64 * 32];
    __shared__ f4 Wr4[64 * 32];
    const int tid = threadIdx.x;
    #pragma unroll
    for (int i = 0; i < 8; ++i) {
        int gg = tid + i * 256;
        int h = gg >> 5, v = gg & 31;
        int slot = (h << 5) | (v ^ (h & 7));
        Wl4[slot] = ((const f4*)W1l)[gg];
        Wr4[slot] = ((const f4*)W1r)[gg];
    }
    __syncthreads();
    const int wave = tid >> 6, lane = tid & 63;
    int e = blockIdx.x * 4 + wave;
    if (e >= N_EDGES) return;
    const int is64 = (flag != nullptr) ? *flag : 0;
    int src = load_idx(ei, is64, e);
    int dst = load_idx(ei, is64, N_EDGES + e);
    float accl = 0.f, accr = 0.f;
    #pragma unroll 4
    for (int v = 0; v < 32; ++v) {
        f4 wl = Wl4[(lane << 5) | (v ^ (lane & 7))];
        f4 wr = Wr4[(lane << 5) | (v ^ (lane & 7))];
        f4 zl = ((const f4*)z)[src * 32 + v];
        f4 zr = ((const f4*)z)[dst * 32 + v];
        accl += wl.x * zl.x + wl.y * zl.y + wl.z * zl.z + wl.w * zl.w;
        accr += wr.x * zr.x + wr.y * zr.y + wr.z * zr.z + wr.w * zr.w;
    }
    float h = lrelu(accl + b1l[lane] + accr + b1r[lane]) * W2[lane];
    #pragma unroll
    for (int off = 32; off; off >>= 1) h += __shfl_xor(h, off, 64);
    if (lane == 0) out[e] = 1.f / (1.f + __expf(-(h + b2[0])));
}

extern "C" void kernel_launch(void* const* d_in, const int* in_sizes, int n_in,
                              void* d_out, int out_size, void* d_ws,
                              size_t ws_size, hipStream_t stream) {
    const float* z   = (const float*)d_in[0];
    const void*  ei  = d_in[1];
    const float* W1l = (const float*)d_in[2];
    const float* b1l = (const float*)d_in[3];
    const float* W1r = (const float*)d_in[4];
    const float* b1r = (const float*)d_in[5];
    const float* W2  = (const float*)d_in[6];
    const float* b2  = (const float*)d_in[7];
    float* out = (float*)d_out;

    const size_t pcomb_bytes = (size_t)N_NODES * 128 * sizeof(u16);  // 25.6 MB
    const size_t need = pcomb_bytes + 256;

    if (ws_size >= need) {
        u16* pcomb = (u16*)d_ws;
        int* flag = (int*)((char*)d_ws + pcomb_bytes);
        node_proj_kernel<<<(N_NODES + 63) / 64, 256, 0, stream>>>(
            z, W1l, b1l, W1r, b1r, (const u32*)ei, flag, pcomb);
        edge_kernel<<<(N_EDGES / 2 * 8 + 255) / 256, 256, 0, stream>>>(
            ei, flag, pcomb, W2, b2, out);
    } else if (ws_size >= 256) {
        int* flag = (int*)d_ws;
        detect_idx_kernel<<<1, 256, 0, stream>>>((const u32*)ei, flag);
        edge_fallback_kernel<<<(N_EDGES + 3) / 4, 256, 0, stream>>>(
            z, ei, flag, W1l, b1l, W1r, b1r, W2, b2, out);
    } else {
        edge_fallback_kernel<<<(N_EDGES + 3) / 4, 256, 0, stream>>>(
            z, ei, nullptr, W1l, b1l, W1r, b1r, W2, b2, out);
    }
}